// Round 3
// baseline (3678.788 us; speedup 1.0000x reference)
//
#include <hip/hip_runtime.h>
#include <cstddef>

// Problem constants: B=16, N=400, MD=8, L=64, H=128, T=8, STEPS=8, COVD=18, ODE_IN=147

// ---- output region offsets (f32 elements, reference return order) ----
constexpr size_t OFF_XHAT  = 0;          // (B,T,N,8)    409600
constexpr size_t OFF_LOGIT = 409600;     // (B,T,N,N)  20480000
constexpr size_t OFF_W     = 20889600;   // (B,T,N,N)  20480000
constexpr size_t OFF_ZM    = 41369600;   // (B,T,N,64)  3276800
constexpr size_t OFF_ZC    = 44646400;   // (B,T,N,64)  3276800
constexpr size_t OFF_MUM   = 47923200;   // (B,N,64)     409600
constexpr size_t OFF_LVM   = 48332800;
constexpr size_t OFF_MUC   = 48742400;
constexpr size_t OFF_LVC   = 49152000;
constexpr size_t OFF_WD    = 49561600;   // duplicate w
constexpr size_t OFF_LNEW  = 70041600;   // total 90521600

// ---- scratch layout (f32 elements) ----
constexpr size_t WS_DIS = 0;        // 6400
constexpr size_t WS_HX  = 6400;     // 51200
constexpr size_t WS_Z   = 57600;    // 819200  (z0 for ODE)
constexpr size_t WS_CB  = 876800;   // 4096    per-batch folded layer1 bias [b][256]
constexpr size_t WS_TOTAL = 880896;

// =============== K1: dis = (rowsum(a0)+1+1e-8)^-0.5, wave per row ===============
__global__ __launch_bounds__(256) void k_dis(const float* __restrict__ a0,
                                             float* __restrict__ dis)
{
    const int lane = threadIdx.x & 63;
    const int wid  = threadIdx.x >> 6;
    const int row  = blockIdx.x * 4 + wid;          // 0..6399 = b*400+i
    const float* arow = a0 + (size_t)row * 400;
    float s = 0.f;
    for (int jj = lane; jj < 400; jj += 64) s += arow[jj];
    #pragma unroll
    for (int off = 32; off > 0; off >>= 1) s += __shfl_down(s, off, 64);
    if (lane == 0) dis[row] = 1.f / sqrtf(s + 1.f + 1e-8f);
}

// =============== K2: hx = a_norm @ x0, block per row ===============
__global__ __launch_bounds__(256) void k_hx(const float* __restrict__ a0,
                                            const float* __restrict__ x0,
                                            const float* __restrict__ dis,
                                            float* __restrict__ hx)
{
    const int row = blockIdx.x;                      // b*400+i
    const int b   = row / 400;
    const int i   = row % 400;
    const float* arow = a0 + (size_t)row * 400;
    const float* disb = dis + b * 400;
    const float* x0b  = x0 + (size_t)b * 400 * 8;
    float acc[8];
    #pragma unroll
    for (int d = 0; d < 8; ++d) acc[d] = 0.f;
    for (int jj = threadIdx.x; jj < 400; jj += 256) {
        const float av = arow[jj] + (jj == i ? 1.f : 0.f);
        const float sc = disb[jj] * av;
        const float4 xa = *(const float4*)&x0b[jj * 8];
        const float4 xb = *(const float4*)&x0b[jj * 8 + 4];
        acc[0] = fmaf(sc, xa.x, acc[0]); acc[1] = fmaf(sc, xa.y, acc[1]);
        acc[2] = fmaf(sc, xa.z, acc[2]); acc[3] = fmaf(sc, xa.w, acc[3]);
        acc[4] = fmaf(sc, xb.x, acc[4]); acc[5] = fmaf(sc, xb.y, acc[5]);
        acc[6] = fmaf(sc, xb.z, acc[6]); acc[7] = fmaf(sc, xb.w, acc[7]);
    }
    __shared__ float red[256][8];
    #pragma unroll
    for (int d = 0; d < 8; ++d) red[threadIdx.x][d] = acc[d];
    __syncthreads();
    for (int st = 128; st > 0; st >>= 1) {
        if ((int)threadIdx.x < st) {
            #pragma unroll
            for (int d = 0; d < 8; ++d) red[threadIdx.x][d] += red[threadIdx.x + st][d];
        }
        __syncthreads();
    }
    if (threadIdx.x < 8)
        hx[(size_t)row * 8 + threadIdx.x] = disb[i] * red[0][threadIdx.x];
}

// =============== K3: encoders -> mu/lv outputs + z0 + zt[t=0] ===============
__global__ __launch_bounds__(256) void k_enc(const float* __restrict__ hx,
    const float* __restrict__ emW1, const float* __restrict__ emb1,
    const float* __restrict__ emWmu, const float* __restrict__ embmu,
    const float* __restrict__ emWlv, const float* __restrict__ emblv,
    const float* __restrict__ ecW1, const float* __restrict__ ecb1,
    const float* __restrict__ ecWmu, const float* __restrict__ ecbmu,
    const float* __restrict__ ecWlv, const float* __restrict__ ecblv,
    float* __restrict__ zws, float* __restrict__ out)
{
    const int row = blockIdx.x;              // b*400+n
    const int b   = row / 400;
    const int n   = row % 400;
    const int tid = threadIdx.x;
    __shared__ float hxs[8];
    __shared__ float hm[128];
    __shared__ float hc[128];
    if (tid < 8) hxs[tid] = hx[(size_t)row * 8 + tid];
    __syncthreads();
    if (tid < 128) {
        float a = emb1[tid];
        #pragma unroll
        for (int d = 0; d < 8; ++d) a = fmaf(hxs[d], emW1[d * 128 + tid], a);
        hm[tid] = fmaxf(a, 0.f);
    } else {
        const int c = tid - 128;
        float a = ecb1[c];
        #pragma unroll
        for (int d = 0; d < 8; ++d) a = fmaf(hxs[d], ecW1[d * 128 + c], a);
        hc[c] = fmaxf(a, 0.f);
    }
    __syncthreads();
    const int grp = tid >> 6;
    const int l   = tid & 63;
    if (grp == 0) {
        float a = embmu[l];
        for (int h = 0; h < 128; ++h) a = fmaf(hm[h], emWmu[h * 64 + l], a);
        out[OFF_MUM + (size_t)row * 64 + l] = a;
        zws[(size_t)row * 128 + l] = a;
        out[OFF_ZM + ((size_t)(b * 8) * 400 + n) * 64 + l] = a;
    } else if (grp == 1) {
        float a = emblv[l];
        for (int h = 0; h < 128; ++h) a = fmaf(hm[h], emWlv[h * 64 + l], a);
        out[OFF_LVM + (size_t)row * 64 + l] = a;
    } else if (grp == 2) {
        float a = ecbmu[l];
        for (int h = 0; h < 128; ++h) a = fmaf(hc[h], ecWmu[h * 64 + l], a);
        out[OFF_MUC + (size_t)row * 64 + l] = a;
        zws[(size_t)row * 128 + 64 + l] = a;
        out[OFF_ZC + ((size_t)(b * 8) * 400 + n) * 64 + l] = a;
    } else {
        float a = ecblv[l];
        for (int h = 0; h < 128; ++h) a = fmaf(hc[h], ecWlv[h * 64 + l], a);
        out[OFF_LVC + (size_t)row * 64 + l] = a;
    }
}

// =============== K4: fold cov into per-batch layer1 bias [b][256] ===============
__global__ __launch_bounds__(256) void k_cb(const int* __restrict__ sex,
    const int* __restrict__ site, const float* __restrict__ covs,
    const float* __restrict__ sexe, const float* __restrict__ sitee,
    const float* __restrict__ omW1, const float* __restrict__ ocW1,
    const float* __restrict__ omb1, const float* __restrict__ ocb1,
    float* __restrict__ cbws)
{
    const int b = blockIdx.x;
    const int tid = threadIdx.x;
    __shared__ float cl[18];
    if (tid < 8)        cl[tid] = sexe[sex[b] * 8 + tid];
    else if (tid < 16)  cl[tid] = sitee[site[b] * 8 + (tid - 8)];
    else if (tid < 18)  cl[tid] = covs[b * 2 + (tid - 16)];
    __syncthreads();
    float a;
    if (tid < 128) {
        a = omb1[tid];
        #pragma unroll
        for (int k = 0; k < 18; ++k) a = fmaf(cl[k], omW1[(128 + k) * 128 + tid], a);
    } else {
        const int c = tid - 128;
        a = ocb1[c];
        #pragma unroll
        for (int k = 0; k < 18; ++k) a = fmaf(cl[k], ocW1[(128 + k) * 128 + c], a);
    }
    cbws[b * 256 + tid] = a;
}

// =============== K5: full RK4 integration, single launch, BARRIER-FREE main loop ===============
// 256 blocks = 1/CU (LDS ~107KB). Block owns 25 rows (3 dummy pad) of one batch.
// Wave w owns row-slots 7w..7w+6 -> zsm/hsm rows are wave-private (same-wave LDS
// ordering handled by compiler lgkmcnt; NO __syncthreads in the main loop).
// W1 (time-invariant, L2-resident 128KB) is streamed per-kq straight from global
// into registers, software-pipelined 1 kq ahead -> zero LDS traffic for W1 and
// no cross-wave coupling. W2 (64KB) stays resident in LDS (latency-critical).
__global__ __launch_bounds__(256, 1) void k_ode(
    const float* __restrict__ times,
    const float* __restrict__ omW1, const float* __restrict__ ocW1,
    const float* __restrict__ omW2, const float* __restrict__ ocW2,
    const float* __restrict__ omb2, const float* __restrict__ ocb2,
    const float* __restrict__ cbws, const float* __restrict__ zws,
    float* __restrict__ out)
{
    __shared__ float W2s[128][128];                 // 64 KB  [h][j] j<64:m j>=64:c
    __shared__ alignas(16) float zsm[28][128];      // 14 KB eval-input rows
    __shared__ alignas(16) float hsm[28][256];      // 28 KB hidden rows

    const int tid  = threadIdx.x;
    const int lane = tid & 63;
    const int wv   = tid >> 6;          // wave 0..3
    const int b    = blockIdx.x >> 4;
    const int n0   = (blockIdx.x & 15) * 25;
    const int r0   = wv * 7;            // row-slot base (slots >=25 are dummy)
    const int c4   = lane * 4;          // layer-1 col base (0..252)
    const int j2   = lane * 2;          // layer-2 output-dim base (0..126)
    const int hoff = (lane < 32) ? 0 : 128;

    // --- load W2s once (only barrier in the kernel) ---
    for (int i = tid; i < 128 * 128; i += 256) {
        const int h = i >> 7, jj = i & 127;
        W2s[h][jj] = (jj < 64) ? omW2[h * 64 + jj] : ocW2[h * 64 + (jj - 64)];
    }

    // --- persistent per-lane constants (registers) ---
    const float4 cb4 = *(const float4*)&cbws[b * 256 + c4];
    const float4 wt4 = (c4 < 128) ? *(const float4*)&omW1[146 * 128 + c4]
                                  : *(const float4*)&ocW1[146 * 128 + (c4 - 128)];
    const float2 b22 = (j2 < 64) ? *(const float2*)&omb2[j2]
                                 : *(const float2*)&ocb2[j2 - 64];
    // W1 column slice base for this lane: wrow + k*128 gives W1[k][c4..c4+3]
    const float* wrow = (c4 < 128) ? omW1 + c4 : ocW1 + (c4 - 128);

    // --- initial state ---
    float2 zst[7], ka[7], kprev[7];
    #pragma unroll
    for (int r = 0; r < 7; ++r) {
        const int slot = r0 + r;
        if (slot < 25)
            zst[r] = *(const float2*)&zws[((size_t)(b * 400) + (n0 + slot)) * 128 + j2];
        else { zst[r].x = 0.f; zst[r].y = 0.f; }
        kprev[r].x = 0.f; kprev[r].y = 0.f;
        ka[r].x = 0.f;    ka[r].y = 0.f;
    }
    __syncthreads();

    for (int idx = 1; idx < 8; ++idx) {
        const float t0 = times[b * 8 + idx - 1];
        const float t1 = times[b * 8 + idx];
        const float hh = (t1 - t0) * 0.125f;
        float tcur = t0;
        #pragma unroll 1
        for (int s = 0; s < 8; ++s) {
            #pragma unroll 1
            for (int st = 0; st < 4; ++st) {
                const float cs  = (st == 0) ? 0.f : ((st == 3) ? 1.f : 0.5f);
                const float csh = cs * hh;
                const float te  = tcur + csh;
                // stage input -> zsm (wave-private rows; same-wave ordering only)
                #pragma unroll
                for (int r = 0; r < 7; ++r) {
                    float2 zi;
                    zi.x = fmaf(csh, kprev[r].x, zst[r].x);
                    zi.y = fmaf(csh, kprev[r].y, zst[r].y);
                    *(float2*)&zsm[r0 + r][j2] = zi;
                }
                // ---- layer 1: acc[7 rows][4 cols], k=0..127 ----
                // weights from GLOBAL (L2-resident), pipelined 1 kq (4 k) ahead
                float4 acc[7];
                #pragma unroll
                for (int r = 0; r < 7; ++r) { acc[r].x = acc[r].y = acc[r].z = acc[r].w = 0.f; }
                float4 wn0 = *(const float4*)&wrow[0 * 128];
                float4 wn1 = *(const float4*)&wrow[1 * 128];
                float4 wn2 = *(const float4*)&wrow[2 * 128];
                float4 wn3 = *(const float4*)&wrow[3 * 128];
                #pragma unroll 1
                for (int kq = 0; kq < 32; ++kq) {
                    const float4 w0 = wn0, w1 = wn1, w2 = wn2, w3 = wn3;
                    if (kq < 31) {
                        const int kn = (kq + 1) * 4;
                        wn0 = *(const float4*)&wrow[(kn + 0) * 128];
                        wn1 = *(const float4*)&wrow[(kn + 1) * 128];
                        wn2 = *(const float4*)&wrow[(kn + 2) * 128];
                        wn3 = *(const float4*)&wrow[(kn + 3) * 128];
                    }
                    const int kb = kq * 4;
                    #pragma unroll
                    for (int r = 0; r < 7; ++r) {
                        const float4 zv = *(const float4*)&zsm[r0 + r][kb];
                        acc[r].x = fmaf(zv.x, w0.x, acc[r].x);
                        acc[r].y = fmaf(zv.x, w0.y, acc[r].y);
                        acc[r].z = fmaf(zv.x, w0.z, acc[r].z);
                        acc[r].w = fmaf(zv.x, w0.w, acc[r].w);
                        acc[r].x = fmaf(zv.y, w1.x, acc[r].x);
                        acc[r].y = fmaf(zv.y, w1.y, acc[r].y);
                        acc[r].z = fmaf(zv.y, w1.z, acc[r].z);
                        acc[r].w = fmaf(zv.y, w1.w, acc[r].w);
                        acc[r].x = fmaf(zv.z, w2.x, acc[r].x);
                        acc[r].y = fmaf(zv.z, w2.y, acc[r].y);
                        acc[r].z = fmaf(zv.z, w2.z, acc[r].z);
                        acc[r].w = fmaf(zv.z, w2.w, acc[r].w);
                        acc[r].x = fmaf(zv.w, w3.x, acc[r].x);
                        acc[r].y = fmaf(zv.w, w3.y, acc[r].y);
                        acc[r].z = fmaf(zv.w, w3.z, acc[r].z);
                        acc[r].w = fmaf(zv.w, w3.w, acc[r].w);
                    }
                }
                // epilogue: bias + t-term + relu -> hsm (wave-private rows)
                {
                    float4 cbv;
                    cbv.x = fmaf(te, wt4.x, cb4.x);
                    cbv.y = fmaf(te, wt4.y, cb4.y);
                    cbv.z = fmaf(te, wt4.z, cb4.z);
                    cbv.w = fmaf(te, wt4.w, cb4.w);
                    #pragma unroll
                    for (int r = 0; r < 7; ++r) {
                        float4 hv;
                        hv.x = fmaxf(acc[r].x + cbv.x, 0.f);
                        hv.y = fmaxf(acc[r].y + cbv.y, 0.f);
                        hv.z = fmaxf(acc[r].z + cbv.z, 0.f);
                        hv.w = fmaxf(acc[r].w + cbv.w, 0.f);
                        *(float4*)&hsm[r0 + r][c4] = hv;
                    }
                }
                // ---- layer 2: kv[7 rows][2 dims], h=0..127 of own net (hoff) ----
                float2 kv[7];
                #pragma unroll
                for (int r = 0; r < 7; ++r) kv[r] = b22;
                #pragma unroll 2
                for (int hq = 0; hq < 32; ++hq) {
                    const float2 wa = *(const float2*)&W2s[hq * 4 + 0][j2];
                    const float2 wb = *(const float2*)&W2s[hq * 4 + 1][j2];
                    const float2 wc = *(const float2*)&W2s[hq * 4 + 2][j2];
                    const float2 wd = *(const float2*)&W2s[hq * 4 + 3][j2];
                    #pragma unroll
                    for (int r = 0; r < 7; ++r) {
                        const float4 hv = *(const float4*)&hsm[r0 + r][hoff + hq * 4];
                        kv[r].x = fmaf(hv.x, wa.x, kv[r].x);
                        kv[r].x = fmaf(hv.y, wb.x, kv[r].x);
                        kv[r].x = fmaf(hv.z, wc.x, kv[r].x);
                        kv[r].x = fmaf(hv.w, wd.x, kv[r].x);
                        kv[r].y = fmaf(hv.x, wa.y, kv[r].y);
                        kv[r].y = fmaf(hv.y, wb.y, kv[r].y);
                        kv[r].y = fmaf(hv.z, wc.y, kv[r].y);
                        kv[r].y = fmaf(hv.w, wd.y, kv[r].y);
                    }
                }
                // ---- RK4 stage combine ----
                const float wst = (st == 1 || st == 2) ? 2.f : 1.f;
                #pragma unroll
                for (int r = 0; r < 7; ++r) {
                    if (st == 0) { ka[r] = kv[r]; }
                    else {
                        ka[r].x = fmaf(wst, kv[r].x, ka[r].x);
                        ka[r].y = fmaf(wst, kv[r].y, ka[r].y);
                    }
                    kprev[r] = kv[r];
                }
            }
            const float h6 = hh * (1.f / 6.f);
            #pragma unroll
            for (int r = 0; r < 7; ++r) {
                zst[r].x = fmaf(h6, ka[r].x, zst[r].x);
                zst[r].y = fmaf(h6, ka[r].y, zst[r].y);
            }
            tcur += hh;
        }
        // write zt[:, idx]
        #pragma unroll
        for (int r = 0; r < 7; ++r) {
            const int slot = r0 + r;
            if (slot < 25) {
                const size_t o = ((size_t)(b * 8 + idx) * 400 + (n0 + slot)) * 64;
                if (j2 < 64) *(float2*)&out[OFF_ZM + o + j2] = zst[r];
                else         *(float2*)&out[OFF_ZC + o + (j2 - 64)] = zst[r];
            }
        }
    }
}

// =============== K6: score = zc zc^T (symmetric tiles) + epilogue ===============
__global__ __launch_bounds__(256) void k_score(const float* __restrict__ out_ro,
    float* __restrict__ out,
    const float* __restrict__ alpha_p, const float* __restrict__ delta_p,
    const float* __restrict__ gamma_p, const float* __restrict__ beta_p,
    const float* __restrict__ alphan_p, const float* __restrict__ deltan_p)
{
    const int blk = blockIdx.x;
    const int bt  = blk / 28;
    int p = blk % 28;
    int ti = 0;
    while (p >= 7 - ti) { p -= 7 - ti; ++ti; }
    const int tj = ti + p;

    __shared__ float As[64][65];
    __shared__ float Bs[64][65];
    const float* zc = out_ro + OFF_ZC + (size_t)bt * 400 * 64;
    for (int i = threadIdx.x; i < 64 * 64; i += 256) {
        const int r = i >> 6, l = i & 63;
        const int gi = ti * 64 + r, gj = tj * 64 + r;
        As[r][l] = (gi < 400) ? zc[(size_t)gi * 64 + l] : 0.f;
        Bs[r][l] = (gj < 400) ? zc[(size_t)gj * 64 + l] : 0.f;
    }
    __syncthreads();

    const int tx = threadIdx.x & 15, ty = threadIdx.x >> 4;
    float c[4][4];
    #pragma unroll
    for (int rr = 0; rr < 4; ++rr)
        #pragma unroll
        for (int cc = 0; cc < 4; ++cc) c[rr][cc] = 0.f;
    for (int k = 0; k < 64; ++k) {
        const float a0v = As[ty * 4 + 0][k], a1v = As[ty * 4 + 1][k];
        const float a2v = As[ty * 4 + 2][k], a3v = As[ty * 4 + 3][k];
        const float b0v = Bs[tx * 4 + 0][k], b1v = Bs[tx * 4 + 1][k];
        const float b2v = Bs[tx * 4 + 2][k], b3v = Bs[tx * 4 + 3][k];
        c[0][0] = fmaf(a0v, b0v, c[0][0]); c[0][1] = fmaf(a0v, b1v, c[0][1]);
        c[0][2] = fmaf(a0v, b2v, c[0][2]); c[0][3] = fmaf(a0v, b3v, c[0][3]);
        c[1][0] = fmaf(a1v, b0v, c[1][0]); c[1][1] = fmaf(a1v, b1v, c[1][1]);
        c[1][2] = fmaf(a1v, b2v, c[1][2]); c[1][3] = fmaf(a1v, b3v, c[1][3]);
        c[2][0] = fmaf(a2v, b0v, c[2][0]); c[2][1] = fmaf(a2v, b1v, c[2][1]);
        c[2][2] = fmaf(a2v, b2v, c[2][2]); c[2][3] = fmaf(a2v, b3v, c[2][3]);
        c[3][0] = fmaf(a3v, b0v, c[3][0]); c[3][1] = fmaf(a3v, b1v, c[3][1]);
        c[3][2] = fmaf(a3v, b2v, c[3][2]); c[3][3] = fmaf(a3v, b3v, c[3][3]);
    }

    const float alpha = *alpha_p, delta = *delta_p, gamma = *gamma_p;
    const float beta = *beta_p, alphan = *alphan_p, deltan = *deltan_p;
    #pragma unroll
    for (int rr = 0; rr < 4; ++rr) {
        #pragma unroll
        for (int cc = 0; cc < 4; ++cc) {
            const int gi = ti * 64 + ty * 4 + rr;
            const int gj = tj * 64 + tx * 4 + cc;
            if (gi < 400 && gj < 400) {
                const float s  = c[rr][cc];
                const float lg = alpha * (s - delta);
                const float ln = alphan * (s - deltan);
                const float x  = fmaf(gamma, s, beta);
                const float sp = fmaxf(x, 0.f) + log1pf(expf(-fabsf(x)));
                const float wvv = (gi == gj) ? 0.f : sp;
                const size_t base  = (size_t)bt * 160000 + (size_t)gi * 400 + gj;
                const size_t baseT = (size_t)bt * 160000 + (size_t)gj * 400 + gi;
                out[OFF_LOGIT + base] = lg;  out[OFF_LOGIT + baseT] = lg;
                out[OFF_W + base]     = wvv; out[OFF_W + baseT]     = wvv;
                out[OFF_WD + base]    = wvv; out[OFF_WD + baseT]    = wvv;
                out[OFF_LNEW + base]  = ln;  out[OFF_LNEW + baseT]  = ln;
            }
        }
    }
}

// =============== K7: decoder x_hat ===============
__global__ __launch_bounds__(256) void k_dec(const float* __restrict__ out_ro,
    const float* __restrict__ W1, const float* __restrict__ b1,
    const float* __restrict__ W2, const float* __restrict__ b2,
    float* __restrict__ out)
{
    __shared__ float W1s[64][128];   // 32 KB
    __shared__ float W2s[128][8];    // 4 KB
    __shared__ float zmS[16][64];
    __shared__ float hS[16][128];
    const int tid = threadIdx.x;
    for (int i = tid; i < 64 * 128; i += 256) W1s[i >> 7][i & 127] = W1[i];
    for (int i = tid; i < 128 * 8; i += 256)  W2s[i >> 3][i & 7]  = W2[i];
    const size_t r0 = (size_t)blockIdx.x * 16;   // rows over B*T*N = 51200
    for (int i = tid; i < 16 * 64; i += 256) {
        const int r = i >> 6, l = i & 63;
        zmS[r][l] = out_ro[OFF_ZM + (r0 + r) * 64 + l];
    }
    __syncthreads();
    const int c = tid & 127, g = tid >> 7;
    for (int rr = 0; rr < 8; ++rr) {
        const int r = g * 8 + rr;
        float a = b1[c];
        for (int l = 0; l < 64; ++l) a = fmaf(zmS[r][l], W1s[l][c], a);
        hS[r][c] = fmaxf(a, 0.f);
    }
    __syncthreads();
    if (tid < 128) {
        const int r = tid >> 3, d = tid & 7;
        float a = b2[d];
        for (int h = 0; h < 128; ++h) a = fmaf(hS[r][h], W2s[h][d], a);
        out[OFF_XHAT + (r0 + r) * 8 + d] = a;
    }
}

// =============== launch ===============
extern "C" void kernel_launch(void* const* d_in, const int* in_sizes, int n_in,
                              void* d_out, int out_size, void* d_ws, size_t ws_size,
                              hipStream_t stream)
{
    const float* a0    = (const float*)d_in[0];
    const float* x0    = (const float*)d_in[1];
    const float* times = (const float*)d_in[2];
    const int*   sex   = (const int*)d_in[3];
    const int*   site  = (const int*)d_in[4];
    const float* covs  = (const float*)d_in[5];
    const float* emW1  = (const float*)d_in[6];
    const float* emb1  = (const float*)d_in[7];
    const float* emWmu = (const float*)d_in[8];
    const float* embmu = (const float*)d_in[9];
    const float* emWlv = (const float*)d_in[10];
    const float* emblv = (const float*)d_in[11];
    const float* ecW1  = (const float*)d_in[12];
    const float* ecb1  = (const float*)d_in[13];
    const float* ecWmu = (const float*)d_in[14];
    const float* ecbmu = (const float*)d_in[15];
    const float* ecWlv = (const float*)d_in[16];
    const float* ecblv = (const float*)d_in[17];
    const float* sexe  = (const float*)d_in[18];
    const float* sitee = (const float*)d_in[19];
    const float* omW1  = (const float*)d_in[20];
    const float* omb1  = (const float*)d_in[21];
    const float* omW2  = (const float*)d_in[22];
    const float* omb2  = (const float*)d_in[23];
    const float* ocW1  = (const float*)d_in[24];
    const float* ocb1  = (const float*)d_in[25];
    const float* ocW2  = (const float*)d_in[26];
    const float* ocb2  = (const float*)d_in[27];
    const float* dmW1  = (const float*)d_in[28];
    const float* dmb1  = (const float*)d_in[29];
    const float* dmW2  = (const float*)d_in[30];
    const float* dmb2  = (const float*)d_in[31];
    const float* alpha_p  = (const float*)d_in[32];
    const float* delta_p  = (const float*)d_in[33];
    const float* gamma_p  = (const float*)d_in[34];
    const float* beta_p   = (const float*)d_in[35];
    const float* alphan_p = (const float*)d_in[36];
    const float* deltan_p = (const float*)d_in[37];

    float* out = (float*)d_out;
    // scratch: prefer d_ws; fall back to aliasing the logit region (written
    // only by k_score, which runs after all scratch consumers).
    float* scratch = (ws_size >= WS_TOTAL * sizeof(float))
                   ? (float*)d_ws : out + OFF_LOGIT;
    float* dis  = scratch + WS_DIS;
    float* hx   = scratch + WS_HX;
    float* zws  = scratch + WS_Z;
    float* cbws = scratch + WS_CB;

    k_dis<<<1600, 256, 0, stream>>>(a0, dis);
    k_hx<<<6400, 256, 0, stream>>>(a0, x0, dis, hx);
    k_enc<<<6400, 256, 0, stream>>>(hx, emW1, emb1, emWmu, embmu, emWlv, emblv,
                                    ecW1, ecb1, ecWmu, ecbmu, ecWlv, ecblv, zws, out);
    k_cb<<<16, 256, 0, stream>>>(sex, site, covs, sexe, sitee, omW1, ocW1, omb1, ocb1, cbws);
    k_ode<<<256, 256, 0, stream>>>(times, omW1, ocW1, omW2, ocW2, omb2, ocb2, cbws, zws, out);
    k_score<<<3584, 256, 0, stream>>>(out, out, alpha_p, delta_p, gamma_p, beta_p, alphan_p, deltan_p);
    k_dec<<<3200, 256, 0, stream>>>(out, dmW1, dmb1, dmW2, dmb2, out);

    (void)in_sizes; (void)n_in; (void)out_size; (void)ws_size;
}

// Round 4
// 3326.268 us; speedup vs baseline: 1.1060x; 1.1060x over previous
//
#include <hip/hip_runtime.h>
#include <cstddef>

// Problem constants: B=16, N=400, MD=8, L=64, H=128, T=8, STEPS=8, COVD=18, ODE_IN=147

// ---- output region offsets (f32 elements, reference return order) ----
constexpr size_t OFF_XHAT  = 0;          // (B,T,N,8)    409600
constexpr size_t OFF_LOGIT = 409600;     // (B,T,N,N)  20480000
constexpr size_t OFF_W     = 20889600;   // (B,T,N,N)  20480000
constexpr size_t OFF_ZM    = 41369600;   // (B,T,N,64)  3276800
constexpr size_t OFF_ZC    = 44646400;   // (B,T,N,64)  3276800
constexpr size_t OFF_MUM   = 47923200;   // (B,N,64)     409600
constexpr size_t OFF_LVM   = 48332800;
constexpr size_t OFF_MUC   = 48742400;
constexpr size_t OFF_LVC   = 49152000;
constexpr size_t OFF_WD    = 49561600;   // duplicate w
constexpr size_t OFF_LNEW  = 70041600;   // total 90521600

// ---- scratch layout (f32 elements) ----
constexpr size_t WS_DIS = 0;        // 6400
constexpr size_t WS_HX  = 6400;     // 51200
constexpr size_t WS_Z   = 57600;    // 819200  (z0 for ODE)
constexpr size_t WS_CB  = 876800;   // 4096    per-batch folded layer1 bias [b][256]
constexpr size_t WS_TOTAL = 880896;

// =============== K1: dis = (rowsum(a0)+1+1e-8)^-0.5, wave per row ===============
__global__ __launch_bounds__(256) void k_dis(const float* __restrict__ a0,
                                             float* __restrict__ dis)
{
    const int lane = threadIdx.x & 63;
    const int wid  = threadIdx.x >> 6;
    const int row  = blockIdx.x * 4 + wid;          // 0..6399 = b*400+i
    const float* arow = a0 + (size_t)row * 400;
    float s = 0.f;
    for (int jj = lane; jj < 400; jj += 64) s += arow[jj];
    #pragma unroll
    for (int off = 32; off > 0; off >>= 1) s += __shfl_down(s, off, 64);
    if (lane == 0) dis[row] = 1.f / sqrtf(s + 1.f + 1e-8f);
}

// =============== K2: hx = a_norm @ x0, block per row ===============
__global__ __launch_bounds__(256) void k_hx(const float* __restrict__ a0,
                                            const float* __restrict__ x0,
                                            const float* __restrict__ dis,
                                            float* __restrict__ hx)
{
    const int row = blockIdx.x;                      // b*400+i
    const int b   = row / 400;
    const int i   = row % 400;
    const float* arow = a0 + (size_t)row * 400;
    const float* disb = dis + b * 400;
    const float* x0b  = x0 + (size_t)b * 400 * 8;
    float acc[8];
    #pragma unroll
    for (int d = 0; d < 8; ++d) acc[d] = 0.f;
    for (int jj = threadIdx.x; jj < 400; jj += 256) {
        const float av = arow[jj] + (jj == i ? 1.f : 0.f);
        const float sc = disb[jj] * av;
        const float4 xa = *(const float4*)&x0b[jj * 8];
        const float4 xb = *(const float4*)&x0b[jj * 8 + 4];
        acc[0] = fmaf(sc, xa.x, acc[0]); acc[1] = fmaf(sc, xa.y, acc[1]);
        acc[2] = fmaf(sc, xa.z, acc[2]); acc[3] = fmaf(sc, xa.w, acc[3]);
        acc[4] = fmaf(sc, xb.x, acc[4]); acc[5] = fmaf(sc, xb.y, acc[5]);
        acc[6] = fmaf(sc, xb.z, acc[6]); acc[7] = fmaf(sc, xb.w, acc[7]);
    }
    __shared__ float red[256][8];
    #pragma unroll
    for (int d = 0; d < 8; ++d) red[threadIdx.x][d] = acc[d];
    __syncthreads();
    for (int st = 128; st > 0; st >>= 1) {
        if ((int)threadIdx.x < st) {
            #pragma unroll
            for (int d = 0; d < 8; ++d) red[threadIdx.x][d] += red[threadIdx.x + st][d];
        }
        __syncthreads();
    }
    if (threadIdx.x < 8)
        hx[(size_t)row * 8 + threadIdx.x] = disb[i] * red[0][threadIdx.x];
}

// =============== K3: encoders -> mu/lv outputs + z0 + zt[t=0] ===============
__global__ __launch_bounds__(256) void k_enc(const float* __restrict__ hx,
    const float* __restrict__ emW1, const float* __restrict__ emb1,
    const float* __restrict__ emWmu, const float* __restrict__ embmu,
    const float* __restrict__ emWlv, const float* __restrict__ emblv,
    const float* __restrict__ ecW1, const float* __restrict__ ecb1,
    const float* __restrict__ ecWmu, const float* __restrict__ ecbmu,
    const float* __restrict__ ecWlv, const float* __restrict__ ecblv,
    float* __restrict__ zws, float* __restrict__ out)
{
    const int row = blockIdx.x;              // b*400+n
    const int b   = row / 400;
    const int n   = row % 400;
    const int tid = threadIdx.x;
    __shared__ float hxs[8];
    __shared__ float hm[128];
    __shared__ float hc[128];
    if (tid < 8) hxs[tid] = hx[(size_t)row * 8 + tid];
    __syncthreads();
    if (tid < 128) {
        float a = emb1[tid];
        #pragma unroll
        for (int d = 0; d < 8; ++d) a = fmaf(hxs[d], emW1[d * 128 + tid], a);
        hm[tid] = fmaxf(a, 0.f);
    } else {
        const int c = tid - 128;
        float a = ecb1[c];
        #pragma unroll
        for (int d = 0; d < 8; ++d) a = fmaf(hxs[d], ecW1[d * 128 + c], a);
        hc[c] = fmaxf(a, 0.f);
    }
    __syncthreads();
    const int grp = tid >> 6;
    const int l   = tid & 63;
    if (grp == 0) {
        float a = embmu[l];
        for (int h = 0; h < 128; ++h) a = fmaf(hm[h], emWmu[h * 64 + l], a);
        out[OFF_MUM + (size_t)row * 64 + l] = a;
        zws[(size_t)row * 128 + l] = a;
        out[OFF_ZM + ((size_t)(b * 8) * 400 + n) * 64 + l] = a;
    } else if (grp == 1) {
        float a = emblv[l];
        for (int h = 0; h < 128; ++h) a = fmaf(hm[h], emWlv[h * 64 + l], a);
        out[OFF_LVM + (size_t)row * 64 + l] = a;
    } else if (grp == 2) {
        float a = ecbmu[l];
        for (int h = 0; h < 128; ++h) a = fmaf(hc[h], ecWmu[h * 64 + l], a);
        out[OFF_MUC + (size_t)row * 64 + l] = a;
        zws[(size_t)row * 128 + 64 + l] = a;
        out[OFF_ZC + ((size_t)(b * 8) * 400 + n) * 64 + l] = a;
    } else {
        float a = ecblv[l];
        for (int h = 0; h < 128; ++h) a = fmaf(hc[h], ecWlv[h * 64 + l], a);
        out[OFF_LVC + (size_t)row * 64 + l] = a;
    }
}

// =============== K4: fold cov into per-batch layer1 bias [b][256] ===============
__global__ __launch_bounds__(256) void k_cb(const int* __restrict__ sex,
    const int* __restrict__ site, const float* __restrict__ covs,
    const float* __restrict__ sexe, const float* __restrict__ sitee,
    const float* __restrict__ omW1, const float* __restrict__ ocW1,
    const float* __restrict__ omb1, const float* __restrict__ ocb1,
    float* __restrict__ cbws)
{
    const int b = blockIdx.x;
    const int tid = threadIdx.x;
    __shared__ float cl[18];
    if (tid < 8)        cl[tid] = sexe[sex[b] * 8 + tid];
    else if (tid < 16)  cl[tid] = sitee[site[b] * 8 + (tid - 8)];
    else if (tid < 18)  cl[tid] = covs[b * 2 + (tid - 16)];
    __syncthreads();
    float a;
    if (tid < 128) {
        a = omb1[tid];
        #pragma unroll
        for (int k = 0; k < 18; ++k) a = fmaf(cl[k], omW1[(128 + k) * 128 + tid], a);
    } else {
        const int c = tid - 128;
        a = ocb1[c];
        #pragma unroll
        for (int k = 0; k < 18; ++k) a = fmaf(cl[k], ocW1[(128 + k) * 128 + c], a);
    }
    cbws[b * 256 + tid] = a;
}

// =============== K5: RK4 integration — 8 waves/block (2/SIMD), row×K-half split ===============
// 256 persistent blocks (1/CU), 512 threads = 8 waves. Block owns 25 rows (28 slots).
// Wave w: row-group g = w&3 (slots 7g..7g+6), K-half kh = w>>2.
//   layer1: wave accumulates k in [64kh, 64kh+64) for its 7 rows x 4 cols/lane.
//   K-half-1 writes partials to LDS; K-half-0 reduces + bias + relu -> hsm.
//   layer2: h-half split the same way (kh covers h in [64kh,64kh+64) of each net).
// W1 streamed per-wave from L2 (each wave only its 64-k half: 524 KB/CU/eval
// < per-CU L2 budget). W2 resident in LDS. 4 barriers per eval.
__global__ __launch_bounds__(512, 2) void k_ode(
    const float* __restrict__ times,
    const float* __restrict__ omW1, const float* __restrict__ ocW1,
    const float* __restrict__ omW2, const float* __restrict__ ocW2,
    const float* __restrict__ omb2, const float* __restrict__ ocb2,
    const float* __restrict__ cbws, const float* __restrict__ zws,
    float* __restrict__ out)
{
    __shared__ float W2s[128][128];                 // 64 KB [h][j] j<64:m j>=64:c
    __shared__ alignas(16) float zsm[28][128];      // 14 KB eval-input rows
    __shared__ alignas(16) float hsm[28][256];      // 28 KB hidden rows (m|c packed)
    __shared__ alignas(16) float part[4][7][256];   // 28 KB cross-wave partials
    // total 134 KB -> 1 block/CU, 8 waves = 2/SIMD

    const int tid  = threadIdx.x;
    const int lane = tid & 63;
    const int wv   = tid >> 6;          // 0..7
    const int g    = wv & 3;            // row group
    const int kh   = wv >> 2;           // k/h half
    const int b    = blockIdx.x >> 4;
    const int n0   = (blockIdx.x & 15) * 25;
    const int r0   = g * 7;             // row-slot base (slots >=25 dummy)
    const int c4   = lane * 4;          // layer-1 col base (0..252, packed m|c)
    const int j2   = lane * 2;          // layer-2 out-dim base (0..126, packed m|c)
    const int hb   = ((lane < 32) ? 0 : 128) + kh * 64;  // hsm col base for layer2
    const int wb   = kh * 64;           // W2s row base for layer2

    // --- load W2s once ---
    for (int i = tid; i < 128 * 128; i += 512) {
        const int h = i >> 7, jj = i & 127;
        W2s[h][jj] = (jj < 64) ? omW2[h * 64 + jj] : ocW2[h * 64 + (jj - 64)];
    }

    // --- per-lane constants ---
    const float4 cb4 = *(const float4*)&cbws[b * 256 + c4];
    const float4 wt4 = (c4 < 128) ? *(const float4*)&omW1[146 * 128 + c4]
                                  : *(const float4*)&ocW1[146 * 128 + (c4 - 128)];
    const float2 b22 = (j2 < 64) ? *(const float2*)&omb2[j2]
                                 : *(const float2*)&ocb2[j2 - 64];
    // W1 column-slice base: wk + k*128 = W1[64*kh + k][c4..c4+3]
    const float* wk = ((c4 < 128) ? omW1 + c4 : ocW1 + (c4 - 128)) + (size_t)(kh * 64) * 128;

    // --- RK4 state (K-half-0 waves own it) ---
    float2 zst[7], ka[7], kprev[7];
    #pragma unroll
    for (int r = 0; r < 7; ++r) {
        const int slot = r0 + r;
        if (kh == 0 && slot < 25)
            zst[r] = *(const float2*)&zws[((size_t)(b * 400) + (n0 + slot)) * 128 + j2];
        else { zst[r].x = 0.f; zst[r].y = 0.f; }
        kprev[r].x = 0.f; kprev[r].y = 0.f;
        ka[r].x = 0.f;    ka[r].y = 0.f;
    }
    __syncthreads();

    for (int idx = 1; idx < 8; ++idx) {
        const float t0 = times[b * 8 + idx - 1];
        const float t1 = times[b * 8 + idx];
        const float hh = (t1 - t0) * 0.125f;
        float tcur = t0;
        #pragma unroll 1
        for (int s = 0; s < 8; ++s) {
            #pragma unroll 1
            for (int st = 0; st < 4; ++st) {
                const float cs  = (st == 0) ? 0.f : ((st == 3) ? 1.f : 0.5f);
                const float csh = cs * hh;
                const float te  = tcur + csh;
                // ---- stage eval input (K-half-0 waves; zeros for dummy slots) ----
                if (kh == 0) {
                    #pragma unroll
                    for (int r = 0; r < 7; ++r) {
                        const int slot = r0 + r;
                        float2 zi;
                        if (slot < 25) {
                            zi.x = fmaf(csh, kprev[r].x, zst[r].x);
                            zi.y = fmaf(csh, kprev[r].y, zst[r].y);
                        } else { zi.x = 0.f; zi.y = 0.f; }
                        *(float2*)&zsm[slot][j2] = zi;
                    }
                }
                __syncthreads();   // A: zsm ready
                // ---- layer 1 (own 64-k half), weights streamed from L2 ----
                float4 acc[7];
                #pragma unroll
                for (int r = 0; r < 7; ++r) { acc[r].x = acc[r].y = acc[r].z = acc[r].w = 0.f; }
                #pragma unroll 4
                for (int kq = 0; kq < 16; ++kq) {
                    const int kb = kq * 4;
                    const float4 w0 = *(const float4*)&wk[(size_t)(kb + 0) * 128];
                    const float4 w1 = *(const float4*)&wk[(size_t)(kb + 1) * 128];
                    const float4 w2 = *(const float4*)&wk[(size_t)(kb + 2) * 128];
                    const float4 w3 = *(const float4*)&wk[(size_t)(kb + 3) * 128];
                    #pragma unroll
                    for (int r = 0; r < 7; ++r) {
                        const float4 zv = *(const float4*)&zsm[r0 + r][kh * 64 + kb];
                        acc[r].x = fmaf(zv.x, w0.x, acc[r].x);
                        acc[r].y = fmaf(zv.x, w0.y, acc[r].y);
                        acc[r].z = fmaf(zv.x, w0.z, acc[r].z);
                        acc[r].w = fmaf(zv.x, w0.w, acc[r].w);
                        acc[r].x = fmaf(zv.y, w1.x, acc[r].x);
                        acc[r].y = fmaf(zv.y, w1.y, acc[r].y);
                        acc[r].z = fmaf(zv.y, w1.z, acc[r].z);
                        acc[r].w = fmaf(zv.y, w1.w, acc[r].w);
                        acc[r].x = fmaf(zv.z, w2.x, acc[r].x);
                        acc[r].y = fmaf(zv.z, w2.y, acc[r].y);
                        acc[r].z = fmaf(zv.z, w2.z, acc[r].z);
                        acc[r].w = fmaf(zv.z, w2.w, acc[r].w);
                        acc[r].x = fmaf(zv.w, w3.x, acc[r].x);
                        acc[r].y = fmaf(zv.w, w3.y, acc[r].y);
                        acc[r].z = fmaf(zv.w, w3.z, acc[r].z);
                        acc[r].w = fmaf(zv.w, w3.w, acc[r].w);
                    }
                }
                if (kh == 1) {
                    #pragma unroll
                    for (int r = 0; r < 7; ++r) *(float4*)&part[g][r][c4] = acc[r];
                }
                __syncthreads();   // B: layer-1 partials ready
                if (kh == 0) {
                    float4 cbv;
                    cbv.x = fmaf(te, wt4.x, cb4.x);
                    cbv.y = fmaf(te, wt4.y, cb4.y);
                    cbv.z = fmaf(te, wt4.z, cb4.z);
                    cbv.w = fmaf(te, wt4.w, cb4.w);
                    #pragma unroll
                    for (int r = 0; r < 7; ++r) {
                        const float4 p = *(const float4*)&part[g][r][c4];
                        float4 hv;
                        hv.x = fmaxf(acc[r].x + p.x + cbv.x, 0.f);
                        hv.y = fmaxf(acc[r].y + p.y + cbv.y, 0.f);
                        hv.z = fmaxf(acc[r].z + p.z + cbv.z, 0.f);
                        hv.w = fmaxf(acc[r].w + p.w + cbv.w, 0.f);
                        *(float4*)&hsm[r0 + r][c4] = hv;
                    }
                }
                __syncthreads();   // C: hsm ready
                // ---- layer 2 (own 64-h half of own net) ----
                float2 kv[7];
                #pragma unroll
                for (int r = 0; r < 7; ++r) {
                    if (kh == 0) kv[r] = b22;
                    else { kv[r].x = 0.f; kv[r].y = 0.f; }
                }
                #pragma unroll 4
                for (int hq = 0; hq < 16; ++hq) {
                    const int h4 = hq * 4;
                    const float2 wa = *(const float2*)&W2s[wb + h4 + 0][j2];
                    const float2 wbv = *(const float2*)&W2s[wb + h4 + 1][j2];
                    const float2 wc = *(const float2*)&W2s[wb + h4 + 2][j2];
                    const float2 wd = *(const float2*)&W2s[wb + h4 + 3][j2];
                    #pragma unroll
                    for (int r = 0; r < 7; ++r) {
                        const float4 hv = *(const float4*)&hsm[r0 + r][hb + h4];
                        kv[r].x = fmaf(hv.x, wa.x, kv[r].x);
                        kv[r].x = fmaf(hv.y, wbv.x, kv[r].x);
                        kv[r].x = fmaf(hv.z, wc.x, kv[r].x);
                        kv[r].x = fmaf(hv.w, wd.x, kv[r].x);
                        kv[r].y = fmaf(hv.x, wa.y, kv[r].y);
                        kv[r].y = fmaf(hv.y, wbv.y, kv[r].y);
                        kv[r].y = fmaf(hv.z, wc.y, kv[r].y);
                        kv[r].y = fmaf(hv.w, wd.y, kv[r].y);
                    }
                }
                if (kh == 1) {
                    #pragma unroll
                    for (int r = 0; r < 7; ++r) *(float2*)&part[g][r][j2] = kv[r];
                }
                __syncthreads();   // D: layer-2 partials ready
                if (kh == 0) {
                    const float wst = (st == 1 || st == 2) ? 2.f : 1.f;
                    #pragma unroll
                    for (int r = 0; r < 7; ++r) {
                        const float2 p = *(const float2*)&part[g][r][j2];
                        float2 kvf;
                        kvf.x = kv[r].x + p.x;
                        kvf.y = kv[r].y + p.y;
                        if (st == 0) { ka[r] = kvf; }
                        else {
                            ka[r].x = fmaf(wst, kvf.x, ka[r].x);
                            ka[r].y = fmaf(wst, kvf.y, ka[r].y);
                        }
                        kprev[r] = kvf;
                    }
                }
            }
            if (kh == 0) {
                const float h6 = hh * (1.f / 6.f);
                #pragma unroll
                for (int r = 0; r < 7; ++r) {
                    zst[r].x = fmaf(h6, ka[r].x, zst[r].x);
                    zst[r].y = fmaf(h6, ka[r].y, zst[r].y);
                }
            }
            tcur += hh;
        }
        // write zt[:, idx] (state owners only)
        if (kh == 0) {
            #pragma unroll
            for (int r = 0; r < 7; ++r) {
                const int slot = r0 + r;
                if (slot < 25) {
                    const size_t o = ((size_t)(b * 8 + idx) * 400 + (n0 + slot)) * 64;
                    if (j2 < 64) *(float2*)&out[OFF_ZM + o + j2] = zst[r];
                    else         *(float2*)&out[OFF_ZC + o + (j2 - 64)] = zst[r];
                }
            }
        }
    }
}

// =============== K6: score = zc zc^T (symmetric tiles) + epilogue ===============
__global__ __launch_bounds__(256) void k_score(const float* __restrict__ out_ro,
    float* __restrict__ out,
    const float* __restrict__ alpha_p, const float* __restrict__ delta_p,
    const float* __restrict__ gamma_p, const float* __restrict__ beta_p,
    const float* __restrict__ alphan_p, const float* __restrict__ deltan_p)
{
    const int blk = blockIdx.x;
    const int bt  = blk / 28;
    int p = blk % 28;
    int ti = 0;
    while (p >= 7 - ti) { p -= 7 - ti; ++ti; }
    const int tj = ti + p;

    __shared__ float As[64][65];
    __shared__ float Bs[64][65];
    const float* zc = out_ro + OFF_ZC + (size_t)bt * 400 * 64;
    for (int i = threadIdx.x; i < 64 * 64; i += 256) {
        const int r = i >> 6, l = i & 63;
        const int gi = ti * 64 + r, gj = tj * 64 + r;
        As[r][l] = (gi < 400) ? zc[(size_t)gi * 64 + l] : 0.f;
        Bs[r][l] = (gj < 400) ? zc[(size_t)gj * 64 + l] : 0.f;
    }
    __syncthreads();

    const int tx = threadIdx.x & 15, ty = threadIdx.x >> 4;
    float c[4][4];
    #pragma unroll
    for (int rr = 0; rr < 4; ++rr)
        #pragma unroll
        for (int cc = 0; cc < 4; ++cc) c[rr][cc] = 0.f;
    for (int k = 0; k < 64; ++k) {
        const float a0v = As[ty * 4 + 0][k], a1v = As[ty * 4 + 1][k];
        const float a2v = As[ty * 4 + 2][k], a3v = As[ty * 4 + 3][k];
        const float b0v = Bs[tx * 4 + 0][k], b1v = Bs[tx * 4 + 1][k];
        const float b2v = Bs[tx * 4 + 2][k], b3v = Bs[tx * 4 + 3][k];
        c[0][0] = fmaf(a0v, b0v, c[0][0]); c[0][1] = fmaf(a0v, b1v, c[0][1]);
        c[0][2] = fmaf(a0v, b2v, c[0][2]); c[0][3] = fmaf(a0v, b3v, c[0][3]);
        c[1][0] = fmaf(a1v, b0v, c[1][0]); c[1][1] = fmaf(a1v, b1v, c[1][1]);
        c[1][2] = fmaf(a1v, b2v, c[1][2]); c[1][3] = fmaf(a1v, b3v, c[1][3]);
        c[2][0] = fmaf(a2v, b0v, c[2][0]); c[2][1] = fmaf(a2v, b1v, c[2][1]);
        c[2][2] = fmaf(a2v, b2v, c[2][2]); c[2][3] = fmaf(a2v, b3v, c[2][3]);
        c[3][0] = fmaf(a3v, b0v, c[3][0]); c[3][1] = fmaf(a3v, b1v, c[3][1]);
        c[3][2] = fmaf(a3v, b2v, c[3][2]); c[3][3] = fmaf(a3v, b3v, c[3][3]);
    }

    const float alpha = *alpha_p, delta = *delta_p, gamma = *gamma_p;
    const float beta = *beta_p, alphan = *alphan_p, deltan = *deltan_p;
    #pragma unroll
    for (int rr = 0; rr < 4; ++rr) {
        #pragma unroll
        for (int cc = 0; cc < 4; ++cc) {
            const int gi = ti * 64 + ty * 4 + rr;
            const int gj = tj * 64 + tx * 4 + cc;
            if (gi < 400 && gj < 400) {
                const float s  = c[rr][cc];
                const float lg = alpha * (s - delta);
                const float ln = alphan * (s - deltan);
                const float x  = fmaf(gamma, s, beta);
                const float sp = fmaxf(x, 0.f) + log1pf(expf(-fabsf(x)));
                const float wvv = (gi == gj) ? 0.f : sp;
                const size_t base  = (size_t)bt * 160000 + (size_t)gi * 400 + gj;
                const size_t baseT = (size_t)bt * 160000 + (size_t)gj * 400 + gi;
                out[OFF_LOGIT + base] = lg;  out[OFF_LOGIT + baseT] = lg;
                out[OFF_W + base]     = wvv; out[OFF_W + baseT]     = wvv;
                out[OFF_WD + base]    = wvv; out[OFF_WD + baseT]    = wvv;
                out[OFF_LNEW + base]  = ln;  out[OFF_LNEW + baseT]  = ln;
            }
        }
    }
}

// =============== K7: decoder x_hat ===============
__global__ __launch_bounds__(256) void k_dec(const float* __restrict__ out_ro,
    const float* __restrict__ W1, const float* __restrict__ b1,
    const float* __restrict__ W2, const float* __restrict__ b2,
    float* __restrict__ out)
{
    __shared__ float W1s[64][128];   // 32 KB
    __shared__ float W2s[128][8];    // 4 KB
    __shared__ float zmS[16][64];
    __shared__ float hS[16][128];
    const int tid = threadIdx.x;
    for (int i = tid; i < 64 * 128; i += 256) W1s[i >> 7][i & 127] = W1[i];
    for (int i = tid; i < 128 * 8; i += 256)  W2s[i >> 3][i & 7]  = W2[i];
    const size_t r0 = (size_t)blockIdx.x * 16;   // rows over B*T*N = 51200
    for (int i = tid; i < 16 * 64; i += 256) {
        const int r = i >> 6, l = i & 63;
        zmS[r][l] = out_ro[OFF_ZM + (r0 + r) * 64 + l];
    }
    __syncthreads();
    const int c = tid & 127, g = tid >> 7;
    for (int rr = 0; rr < 8; ++rr) {
        const int r = g * 8 + rr;
        float a = b1[c];
        for (int l = 0; l < 64; ++l) a = fmaf(zmS[r][l], W1s[l][c], a);
        hS[r][c] = fmaxf(a, 0.f);
    }
    __syncthreads();
    if (tid < 128) {
        const int r = tid >> 3, d = tid & 7;
        float a = b2[d];
        for (int h = 0; h < 128; ++h) a = fmaf(hS[r][h], W2s[h][d], a);
        out[OFF_XHAT + (r0 + r) * 8 + d] = a;
    }
}

// =============== launch ===============
extern "C" void kernel_launch(void* const* d_in, const int* in_sizes, int n_in,
                              void* d_out, int out_size, void* d_ws, size_t ws_size,
                              hipStream_t stream)
{
    const float* a0    = (const float*)d_in[0];
    const float* x0    = (const float*)d_in[1];
    const float* times = (const float*)d_in[2];
    const int*   sex   = (const int*)d_in[3];
    const int*   site  = (const int*)d_in[4];
    const float* covs  = (const float*)d_in[5];
    const float* emW1  = (const float*)d_in[6];
    const float* emb1  = (const float*)d_in[7];
    const float* emWmu = (const float*)d_in[8];
    const float* embmu = (const float*)d_in[9];
    const float* emWlv = (const float*)d_in[10];
    const float* emblv = (const float*)d_in[11];
    const float* ecW1  = (const float*)d_in[12];
    const float* ecb1  = (const float*)d_in[13];
    const float* ecWmu = (const float*)d_in[14];
    const float* ecbmu = (const float*)d_in[15];
    const float* ecWlv = (const float*)d_in[16];
    const float* ecblv = (const float*)d_in[17];
    const float* sexe  = (const float*)d_in[18];
    const float* sitee = (const float*)d_in[19];
    const float* omW1  = (const float*)d_in[20];
    const float* omb1  = (const float*)d_in[21];
    const float* omW2  = (const float*)d_in[22];
    const float* omb2  = (const float*)d_in[23];
    const float* ocW1  = (const float*)d_in[24];
    const float* ocb1  = (const float*)d_in[25];
    const float* ocW2  = (const float*)d_in[26];
    const float* ocb2  = (const float*)d_in[27];
    const float* dmW1  = (const float*)d_in[28];
    const float* dmb1  = (const float*)d_in[29];
    const float* dmW2  = (const float*)d_in[30];
    const float* dmb2  = (const float*)d_in[31];
    const float* alpha_p  = (const float*)d_in[32];
    const float* delta_p  = (const float*)d_in[33];
    const float* gamma_p  = (const float*)d_in[34];
    const float* beta_p   = (const float*)d_in[35];
    const float* alphan_p = (const float*)d_in[36];
    const float* deltan_p = (const float*)d_in[37];

    float* out = (float*)d_out;
    // scratch: prefer d_ws; fall back to aliasing the logit region (written
    // only by k_score, which runs after all scratch consumers).
    float* scratch = (ws_size >= WS_TOTAL * sizeof(float))
                   ? (float*)d_ws : out + OFF_LOGIT;
    float* dis  = scratch + WS_DIS;
    float* hx   = scratch + WS_HX;
    float* zws  = scratch + WS_Z;
    float* cbws = scratch + WS_CB;

    k_dis<<<1600, 256, 0, stream>>>(a0, dis);
    k_hx<<<6400, 256, 0, stream>>>(a0, x0, dis, hx);
    k_enc<<<6400, 256, 0, stream>>>(hx, emW1, emb1, emWmu, embmu, emWlv, emblv,
                                    ecW1, ecb1, ecWmu, ecbmu, ecWlv, ecblv, zws, out);
    k_cb<<<16, 256, 0, stream>>>(sex, site, covs, sexe, sitee, omW1, ocW1, omb1, ocb1, cbws);
    k_ode<<<256, 512, 0, stream>>>(times, omW1, ocW1, omW2, ocW2, omb2, ocb2, cbws, zws, out);
    k_score<<<3584, 256, 0, stream>>>(out, out, alpha_p, delta_p, gamma_p, beta_p, alphan_p, deltan_p);
    k_dec<<<3200, 256, 0, stream>>>(out, dmW1, dmb1, dmW2, dmb2, out);

    (void)in_sizes; (void)n_in; (void)out_size; (void)ws_size;
}